// Round 1
// baseline (2090.218 us; speedup 1.0000x reference)
//
#include <hip/hip_runtime.h>

// PDA_GNN: 3-branch LightGCN + L2-normalize + fused attention MLP.
// N=100000 nodes, E=1250000 edges per graph, D=64 features.

constexpr int NN = 100000;
constexpr int NE = 1250000;
constexpr int FD = 64;

// ---------------------------------------------------------------------------
// Degree count: deg[dst[e]] += 1  (in-degree only, per reference semantics)
// ---------------------------------------------------------------------------
__global__ __launch_bounds__(256) void k_deg(const int* __restrict__ dst,
                                             float* __restrict__ deg) {
    int i = blockIdx.x * blockDim.x + threadIdx.x;
    if (i < NE) atomicAdd(&deg[dst[i]], 1.0f);
}

// dinv = deg > 0 ? deg^-0.5 : 0   (in place, over 3*N contiguous floats)
__global__ __launch_bounds__(256) void k_dinv(float* __restrict__ d, int n) {
    int i = blockIdx.x * blockDim.x + threadIdx.x;
    if (i < n) {
        float v = d[i];
        d[i] = (v > 0.0f) ? (1.0f / sqrtf(v)) : 0.0f;
    }
}

// ---------------------------------------------------------------------------
// LGConv: one wave (64 lanes) per edge; lane d handles feature d.
// y[dst] += dinv[src]*dinv[dst] * x[src]   (y must be pre-zeroed)
// ---------------------------------------------------------------------------
__global__ __launch_bounds__(256) void k_conv(const float* __restrict__ x,
                                              float* __restrict__ y,
                                              const int* __restrict__ src,
                                              const int* __restrict__ dst,
                                              const float* __restrict__ dinv) {
    int gid = blockIdx.x * blockDim.x + threadIdx.x;   // < NE*64 = 80M, fits int
    int e = gid >> 6;
    int lane = gid & 63;
    if (e >= NE) return;
    int s = src[e];
    int t = dst[e];
    float nrm = dinv[s] * dinv[t];
    float v = nrm * x[s * FD + lane];
    atomicAdd(&y[t * FD + lane], v);
}

// ---------------------------------------------------------------------------
// Fused: L2-normalize 3 branches, concat, h=relu(x@W1+b1), att=softmax(h@W2+b2),
// out = att0*xt + att1*xy + att2*xc.  One wave per node, 4 nodes per block.
// 100000 / 4 = 25000 blocks exactly (no tail).
// ---------------------------------------------------------------------------
__global__ __launch_bounds__(256) void k_final(const float* __restrict__ xt,
                                               const float* __restrict__ xy,
                                               const float* __restrict__ xc,
                                               const float* __restrict__ W1,
                                               const float* __restrict__ b1,
                                               const float* __restrict__ W2,
                                               const float* __restrict__ b2,
                                               float* __restrict__ out) {
    __shared__ float xall[4][192];
    const int wave = threadIdx.x >> 6;
    const int lane = threadIdx.x & 63;
    const int node = blockIdx.x * 4 + wave;

    const int base = node * FD + lane;
    float t = xt[base];
    float y = xy[base];
    float c = xc[base];

    // wave-wide sum of squares (full butterfly -> every lane has the total)
    float sst = t * t, ssy = y * y, ssc = c * c;
    #pragma unroll
    for (int off = 32; off > 0; off >>= 1) {
        sst += __shfl_xor(sst, off);
        ssy += __shfl_xor(ssy, off);
        ssc += __shfl_xor(ssc, off);
    }
    t /= fmaxf(sqrtf(sst), 1e-12f);
    y /= fmaxf(sqrtf(ssy), 1e-12f);
    c /= fmaxf(sqrtf(ssc), 1e-12f);

    xall[wave][lane]       = t;
    xall[wave][64 + lane]  = y;
    xall[wave][128 + lane] = c;
    __syncthreads();

    // layer 1: lane j computes h[j] and h[j+64]
    const float* xa = xall[wave];
    float acc0 = b1[lane];
    float acc1 = b1[lane + 64];
    #pragma unroll 8
    for (int k = 0; k < 192; ++k) {
        float xk = xa[k];
        acc0 = fmaf(xk, W1[k * 128 + lane], acc0);
        acc1 = fmaf(xk, W1[k * 128 + lane + 64], acc1);
    }
    acc0 = fmaxf(acc0, 0.0f);
    acc1 = fmaxf(acc1, 0.0f);

    // layer 2: 3 logits, partial per lane then wave reduce
    float l0 = fmaf(acc0, W2[lane * 3 + 0], acc1 * W2[(lane + 64) * 3 + 0]);
    float l1 = fmaf(acc0, W2[lane * 3 + 1], acc1 * W2[(lane + 64) * 3 + 1]);
    float l2 = fmaf(acc0, W2[lane * 3 + 2], acc1 * W2[(lane + 64) * 3 + 2]);
    #pragma unroll
    for (int off = 32; off > 0; off >>= 1) {
        l0 += __shfl_xor(l0, off);
        l1 += __shfl_xor(l1, off);
        l2 += __shfl_xor(l2, off);
    }
    l0 += b2[0];
    l1 += b2[1];
    l2 += b2[2];

    // softmax over 3 (uniform across lanes)
    float m = fmaxf(l0, fmaxf(l1, l2));
    float e0 = __expf(l0 - m), e1 = __expf(l1 - m), e2 = __expf(l2 - m);
    float inv = 1.0f / (e0 + e1 + e2);

    out[base] = (e0 * t + e1 * y + e2 * c) * inv;
}

// ---------------------------------------------------------------------------
extern "C" void kernel_launch(void* const* d_in, const int* in_sizes, int n_in,
                              void* d_out, int out_size, void* d_ws, size_t ws_size,
                              hipStream_t stream) {
    const float* init_feat = (const float*)d_in[0];
    const float* W1 = (const float*)d_in[1];
    const float* b1 = (const float*)d_in[2];
    const float* W2 = (const float*)d_in[3];
    const float* b2 = (const float*)d_in[4];
    const int* ei_title = (const int*)d_in[5];   // [2, E]: row0=src, row1=dst
    const int* ei_year  = (const int*)d_in[6];
    const int* ei_cat   = (const int*)d_in[7];
    float* out = (float*)d_out;

    float* ws = (float*)d_ws;
    float* dinv_t = ws;                 // N
    float* dinv_y = ws + NN;            // N
    float* dinv_c = ws + 2 * NN;        // N
    float* B1 = ws + 3 * NN;            // N*D
    float* B2 = B1 + NN * FD;
    float* B3 = B2 + NN * FD;
    float* B4 = B3 + NN * FD;

    const int TB = 256;
    const int degGrid  = (NE + TB - 1) / TB;
    const int convGrid = NE / 4;                 // NE*64 threads / 256
    const size_t rowBytes = (size_t)NN * FD * sizeof(float);

    // degrees -> dinv (all three edge sets)
    hipMemsetAsync(ws, 0, 3 * NN * sizeof(float), stream);
    k_deg<<<degGrid, TB, 0, stream>>>(ei_title + NE, dinv_t);
    k_deg<<<degGrid, TB, 0, stream>>>(ei_year + NE, dinv_y);
    k_deg<<<degGrid, TB, 0, stream>>>(ei_cat + NE, dinv_c);
    k_dinv<<<(3 * NN + TB - 1) / TB, TB, 0, stream>>>(ws, 3 * NN);

    // title: 2 convs
    hipMemsetAsync(B1, 0, rowBytes, stream);
    k_conv<<<convGrid, TB, 0, stream>>>(init_feat, B1, ei_title, ei_title + NE, dinv_t);
    hipMemsetAsync(B2, 0, rowBytes, stream);
    k_conv<<<convGrid, TB, 0, stream>>>(B1, B2, ei_title, ei_title + NE, dinv_t);
    // year: 1 conv
    hipMemsetAsync(B3, 0, rowBytes, stream);
    k_conv<<<convGrid, TB, 0, stream>>>(init_feat, B3, ei_year, ei_year + NE, dinv_y);
    // cat: 3 convs
    hipMemsetAsync(B4, 0, rowBytes, stream);
    k_conv<<<convGrid, TB, 0, stream>>>(init_feat, B4, ei_cat, ei_cat + NE, dinv_c);
    hipMemsetAsync(B1, 0, rowBytes, stream);
    k_conv<<<convGrid, TB, 0, stream>>>(B4, B1, ei_cat, ei_cat + NE, dinv_c);
    hipMemsetAsync(B4, 0, rowBytes, stream);
    k_conv<<<convGrid, TB, 0, stream>>>(B1, B4, ei_cat, ei_cat + NE, dinv_c);

    // fused normalize + concat + MLP + softmax + weighted sum
    k_final<<<NN / 4, TB, 0, stream>>>(B2, B3, B4, W1, b1, W2, b2, out);
}

// Round 2
// 951.514 us; speedup vs baseline: 2.1967x; 2.1967x over previous
//
#include <hip/hip_runtime.h>

// PDA_GNN: 3-branch LightGCN (CSR gather convs) + fused normalize/concat/MLP/softmax.
// N=100000 nodes, E=1250000 edges per graph, D=64 features.

constexpr int NN = 100000;
constexpr int NE = 1250000;

// ---------------------------------------------------------------------------
// In-degree count (int atomics)
// ---------------------------------------------------------------------------
__global__ __launch_bounds__(256) void k_cnt(const int* __restrict__ dst, int* __restrict__ cnt) {
    int i = blockIdx.x * 256 + threadIdx.x;
    if (i < NE) atomicAdd(&cnt[dst[i]], 1);
}

// dinv = cnt > 0 ? cnt^-0.5 : 0, over all 3*N entries
__global__ __launch_bounds__(256) void k_dinv(const int* __restrict__ cnt, float* __restrict__ dinv) {
    int i = blockIdx.x * 256 + threadIdx.x;
    if (i < 3 * NN) {
        int c = cnt[i];
        dinv[i] = (c > 0) ? (1.0f / sqrtf((float)c)) : 0.0f;
    }
}

// ---------------------------------------------------------------------------
// Allocate a contiguous csr range per row: wave-scan of counts + one atomic
// per wave on a global cursor. Row placement order is irrelevant to the gather.
// ---------------------------------------------------------------------------
__global__ __launch_bounds__(256) void k_alloc(const int* __restrict__ cnt, int* __restrict__ rowstart,
                                               int* __restrict__ counter) {
    int i = blockIdx.x * 256 + threadIdx.x;
    int lane = threadIdx.x & 63;
    int v = (i < NN) ? cnt[i] : 0;
    int incl = v;
    #pragma unroll
    for (int off = 1; off < 64; off <<= 1) {
        int u = __shfl_up(incl, off);
        if (lane >= off) incl += u;
    }
    int total = __shfl(incl, 63);
    int base = 0;
    if (lane == 63) base = atomicAdd(counter, total);
    base = __shfl(base, 63);
    if (i < NN) rowstart[i] = base + incl - v;
}

// Scatter src indices into csr slots (atomic per-row cursor)
__global__ __launch_bounds__(256) void k_scatter(const int* __restrict__ src, const int* __restrict__ dst,
                                                 const int* __restrict__ rowstart, int* __restrict__ cursor,
                                                 int* __restrict__ csr) {
    int e = blockIdx.x * 256 + threadIdx.x;
    if (e < NE) {
        int t = dst[e];
        int p = rowstart[t] + atomicAdd(&cursor[t], 1);
        csr[p] = src[e];
    }
}

// ---------------------------------------------------------------------------
// LGConv as gather: one wave per dst node, lane d = feature d.
// y[t][d] = dinv[t] * sum_{s in in(t)} dinv[s] * x[s][d]
// ---------------------------------------------------------------------------
__global__ __launch_bounds__(256) void k_gather(const float* __restrict__ x, float* __restrict__ y,
                                                const int* __restrict__ csr, const int* __restrict__ rowstart,
                                                const int* __restrict__ cnt, const float* __restrict__ dinv) {
    int node = blockIdx.x * 4 + (threadIdx.x >> 6);
    int lane = threadIdx.x & 63;
    const int* lst = csr + rowstart[node];
    int n = cnt[node];
    float acc = 0.0f;
    int i = 0;
    for (; i + 4 <= n; i += 4) {
        int s0 = lst[i], s1 = lst[i + 1], s2 = lst[i + 2], s3 = lst[i + 3];
        float a0 = dinv[s0] * x[s0 * 64 + lane];
        float a1 = dinv[s1] * x[s1 * 64 + lane];
        float a2 = dinv[s2] * x[s2 * 64 + lane];
        float a3 = dinv[s3] * x[s3 * 64 + lane];
        acc += (a0 + a1) + (a2 + a3);
    }
    for (; i < n; ++i) {
        int s = lst[i];
        acc += dinv[s] * x[s * 64 + lane];
    }
    y[node * 64 + lane] = dinv[node] * acc;
}

// ---------------------------------------------------------------------------
// Fused: normalize 3 branches -> Xs[k][m] (transposed in LDS), register-tiled
// GEMM H = relu(X@W1+b1) (64 nodes x 128 cols per block, 8x4 micro-tile),
// logits via half-wave shfl reduce, softmax, weighted sum of normalized rows.
// ---------------------------------------------------------------------------
__global__ __launch_bounds__(256) void k_final(const float* xt, const float* xy, const float* xc,
                                               const float* __restrict__ W1, const float* __restrict__ b1,
                                               const float* __restrict__ W2, const float* __restrict__ b2,
                                               float* out) {
    __shared__ float Xs[192][68];   // 52224 B; pad 68: float4-aligned rows, 8-way on transpose writes
    __shared__ float Ws[16][128];   // 8192 B
    __shared__ float lg[64][3];     // logits
    const int tid = threadIdx.x;
    const int wave = tid >> 6, lane = tid & 63;
    const int nbase = blockIdx.x * 64;

    // ---- phase 1: per-node L2 normalize, write transposed into Xs
    for (int i = 0; i < 16; ++i) {
        int m = i * 4 + wave;
        int node = nbase + m;
        float t = 0.f, y = 0.f, c = 0.f;
        if (node < NN) {
            int base = node * 64 + lane;
            t = xt[base]; y = xy[base]; c = xc[base];
        }
        float sst = t * t, ssy = y * y, ssc = c * c;
        #pragma unroll
        for (int off = 32; off > 0; off >>= 1) {
            sst += __shfl_xor(sst, off);
            ssy += __shfl_xor(ssy, off);
            ssc += __shfl_xor(ssc, off);
        }
        t /= fmaxf(sqrtf(sst), 1e-12f);
        y /= fmaxf(sqrtf(ssy), 1e-12f);
        c /= fmaxf(sqrtf(ssc), 1e-12f);
        Xs[lane][m]       = t;
        Xs[64 + lane][m]  = y;
        Xs[128 + lane][m] = c;
    }

    // ---- phase 2: H = relu(X @ W1 + b1), thread = 8 nodes x 4 cols
    const int cg = tid & 31;   // col group: cols cg*4 .. cg*4+3
    const int rg = tid >> 5;   // row group: nodes rg*8 .. rg*8+7
    float bj[4];
    #pragma unroll
    for (int j = 0; j < 4; ++j) bj[j] = b1[cg * 4 + j];
    float acc[8][4];
    #pragma unroll
    for (int i = 0; i < 8; ++i)
        #pragma unroll
        for (int j = 0; j < 4; ++j) acc[i][j] = bj[j];

    for (int kc = 0; kc < 192; kc += 16) {
        __syncthreads();   // protects Ws reuse (and, first time, Xs writes)
        #pragma unroll
        for (int u = 0; u < 2; ++u)
            ((float4*)Ws)[u * 256 + tid] = ((const float4*)(W1 + kc * 128))[u * 256 + tid];
        __syncthreads();
        #pragma unroll 4
        for (int kk = 0; kk < 16; ++kk) {
            float4 x0 = *(const float4*)&Xs[kc + kk][rg * 8];
            float4 x1 = *(const float4*)&Xs[kc + kk][rg * 8 + 4];
            float4 wv = *(const float4*)&Ws[kk][cg * 4];
            float xv[8] = {x0.x, x0.y, x0.z, x0.w, x1.x, x1.y, x1.z, x1.w};
            float wj[4] = {wv.x, wv.y, wv.z, wv.w};
            #pragma unroll
            for (int i = 0; i < 8; ++i)
                #pragma unroll
                for (int j = 0; j < 4; ++j)
                    acc[i][j] = fmaf(xv[i], wj[j], acc[i][j]);
        }
    }

    // ---- epilogue: logits = relu(H) @ W2, reduce across the 32-thread col groups
    float w2c[4][3];
    #pragma unroll
    for (int j = 0; j < 4; ++j)
        #pragma unroll
        for (int q = 0; q < 3; ++q) w2c[j][q] = W2[(cg * 4 + j) * 3 + q];

    #pragma unroll
    for (int i = 0; i < 8; ++i) {
        float p0 = 0.f, p1 = 0.f, p2 = 0.f;
        #pragma unroll
        for (int j = 0; j < 4; ++j) {
            float h = fmaxf(acc[i][j], 0.f);
            p0 = fmaf(h, w2c[j][0], p0);
            p1 = fmaf(h, w2c[j][1], p1);
            p2 = fmaf(h, w2c[j][2], p2);
        }
        #pragma unroll
        for (int off = 16; off > 0; off >>= 1) {  // stays within the 32-lane half
            p0 += __shfl_xor(p0, off);
            p1 += __shfl_xor(p1, off);
            p2 += __shfl_xor(p2, off);
        }
        if (cg == 0) {
            lg[rg * 8 + i][0] = p0;
            lg[rg * 8 + i][1] = p1;
            lg[rg * 8 + i][2] = p2;
        }
    }
    __syncthreads();

    // ---- softmax + weighted sum, coalesced output
    for (int g = 0; g < 16; ++g) {
        int m = g * 4 + wave;
        int node = nbase + m;
        if (node < NN) {
            float l0 = lg[m][0] + b2[0];
            float l1 = lg[m][1] + b2[1];
            float l2 = lg[m][2] + b2[2];
            float mx = fmaxf(l0, fmaxf(l1, l2));
            float e0 = __expf(l0 - mx), e1 = __expf(l1 - mx), e2 = __expf(l2 - mx);
            float inv = 1.0f / (e0 + e1 + e2);
            float t = Xs[lane][m], y = Xs[64 + lane][m], c = Xs[128 + lane][m];
            out[node * 64 + lane] = (e0 * t + e1 * y + e2 * c) * inv;
        }
    }
}

// ---------------------------------------------------------------------------
extern "C" void kernel_launch(void* const* d_in, const int* in_sizes, int n_in,
                              void* d_out, int out_size, void* d_ws, size_t ws_size,
                              hipStream_t stream) {
    const float* init_feat = (const float*)d_in[0];
    const float* W1 = (const float*)d_in[1];
    const float* b1 = (const float*)d_in[2];
    const float* W2 = (const float*)d_in[3];
    const float* b2 = (const float*)d_in[4];
    const int* ei[3] = {(const int*)d_in[5], (const int*)d_in[6], (const int*)d_in[7]}; // title, year, cat

    float* TMP = (float*)d_out;   // d_out doubles as ping-pong temp (fully rewritten before reads)

    // workspace layout
    float* B1 = (float*)d_ws;                     // title out   [N*64]
    float* B2 = B1 + (size_t)NN * 64;             // year out    [N*64]
    float* B3 = B2 + (size_t)NN * 64;             // cat temp    [N*64]
    float* dinvA = B3 + (size_t)NN * 64;          // [3*N] f32
    int* cntA = (int*)(dinvA + 3 * NN);           // [3*N]
    int* curA = cntA + 3 * NN;                    // [3*N]
    int* allocA = curA + 3 * NN;                  // [4]
    int* rowA = allocA + 4;                       // [3*N]
    int* csrA = rowA + 3 * NN;                    // [3*E]

    const int TB = 256;
    const int eGrid = (NE + TB - 1) / TB;         // 4883
    const int nGrid = (NN + TB - 1) / TB;         // 391
    const int gatherGrid = NN / 4;                // 25000 (exact)
    const int finalGrid = (NN + 63) / 64;         // 1563

    // zero cnt, cursor, alloc counters in one memset
    hipMemsetAsync(cntA, 0, (size_t)(6 * NN + 4) * sizeof(int), stream);

    // CSR build per edge set
    for (int s = 0; s < 3; ++s)
        k_cnt<<<eGrid, TB, 0, stream>>>(ei[s] + NE, cntA + s * NN);
    k_dinv<<<(3 * NN + TB - 1) / TB, TB, 0, stream>>>(cntA, dinvA);
    for (int s = 0; s < 3; ++s)
        k_alloc<<<nGrid, TB, 0, stream>>>(cntA + s * NN, rowA + s * NN, allocA + s);
    for (int s = 0; s < 3; ++s)
        k_scatter<<<eGrid, TB, 0, stream>>>(ei[s], ei[s] + NE, rowA + s * NN,
                                            curA + s * NN, csrA + (size_t)s * NE);

    // convs: title x2, year x1, cat x3
    #define GATHER(xp, yp, s) \
        k_gather<<<gatherGrid, TB, 0, stream>>>((xp), (yp), csrA + (size_t)(s) * NE, \
                                                rowA + (s) * NN, cntA + (s) * NN, dinvA + (s) * NN)
    GATHER(init_feat, TMP, 0);   // title conv 1
    GATHER(TMP, B1, 0);          // title conv 2 -> B1
    GATHER(init_feat, B2, 1);    // year conv    -> B2
    GATHER(init_feat, TMP, 2);   // cat conv 1
    GATHER(TMP, B3, 2);          // cat conv 2
    GATHER(B3, TMP, 2);          // cat conv 3   -> TMP (= d_out)
    #undef GATHER

    // fused tail: xt=B1, xy=B2, xc=TMP, writes d_out (block-local rows, safe alias)
    k_final<<<finalGrid, TB, 0, stream>>>(B1, B2, TMP, W1, b1, W2, b2, TMP);
}

// Round 3
// 856.330 us; speedup vs baseline: 2.4409x; 1.1112x over previous
//
#include <hip/hip_runtime.h>

// PDA_GNN: 3-branch LightGCN (CSR gather convs, float4/16-lanes-per-edge) +
// fused normalize/concat/MLP/softmax. N=100000, E=1250000, D=64.

constexpr int NN = 100000;
constexpr int NE = 1250000;

// ---------------------------------------------------------------------------
// In-degree count for all 3 edge sets in one launch
// ---------------------------------------------------------------------------
__global__ __launch_bounds__(256) void k_cnt3(const int* __restrict__ e0, const int* __restrict__ e1,
                                              const int* __restrict__ e2, int* __restrict__ cnt) {
    int i = blockIdx.x * 256 + threadIdx.x;
    if (i < NE) atomicAdd(&cnt[e0[NE + i]], 1);
    else if (i < 2 * NE) atomicAdd(&cnt[NN + e1[NE + i - NE]], 1);
    else if (i < 3 * NE) atomicAdd(&cnt[2 * NN + e2[NE + i - 2 * NE]], 1);
}

// dinv = cnt > 0 ? cnt^-0.5 : 0, over all 3*N entries
__global__ __launch_bounds__(256) void k_dinv(const int* __restrict__ cnt, float* __restrict__ dinv) {
    int i = blockIdx.x * 256 + threadIdx.x;
    if (i < 3 * NN) {
        int c = cnt[i];
        dinv[i] = (c > 0) ? (1.0f / sqrtf((float)c)) : 0.0f;
    }
}

// ---------------------------------------------------------------------------
// Allocate contiguous csr range per row: wave-scan + one atomic per wave.
// Row placement order is irrelevant to the gather.
// ---------------------------------------------------------------------------
__global__ __launch_bounds__(256) void k_alloc(const int* __restrict__ cnt, int* __restrict__ rowstart,
                                               int* __restrict__ counter) {
    int i = blockIdx.x * 256 + threadIdx.x;
    int lane = threadIdx.x & 63;
    int v = (i < NN) ? cnt[i] : 0;
    int incl = v;
    #pragma unroll
    for (int off = 1; off < 64; off <<= 1) {
        int u = __shfl_up(incl, off);
        if (lane >= off) incl += u;
    }
    int total = __shfl(incl, 63);
    int base = 0;
    if (lane == 63) base = atomicAdd(counter, total);
    base = __shfl(base, 63);
    if (i < NN) rowstart[i] = base + incl - v;
}

// Scatter src indices into csr slots for all 3 sets (atomic per-row cursor)
__global__ __launch_bounds__(256) void k_scat3(const int* __restrict__ e0, const int* __restrict__ e1,
                                               const int* __restrict__ e2, const int* __restrict__ rowstart,
                                               int* __restrict__ cursor, int* __restrict__ csr) {
    int i = blockIdx.x * 256 + threadIdx.x;
    const int* ei; int set, e;
    if (i < NE)           { ei = e0; set = 0; e = i; }
    else if (i < 2 * NE)  { ei = e1; set = 1; e = i - NE; }
    else if (i < 3 * NE)  { ei = e2; set = 2; e = i - 2 * NE; }
    else return;
    int s = ei[e], t = set * NN + ei[NE + e];
    int p = rowstart[t] + atomicAdd(&cursor[t], 1);
    csr[(size_t)set * NE + p] = s;
}

// ---------------------------------------------------------------------------
// LGConv gather: one wave per dst node; 16 lanes per edge (float4 per lane),
// 4 edges per iteration, 2-deep unroll (8 edge rows in flight per wave).
// y[t] = dinv[t] * sum_{s in in(t)} dinv[s] * x[s]
// ---------------------------------------------------------------------------
__global__ __launch_bounds__(256) void k_gather(const float* __restrict__ x, float* __restrict__ y,
                                                const int* __restrict__ csr, const int* __restrict__ rowstart,
                                                const int* __restrict__ cnt, const float* __restrict__ dinv) {
    const int node = blockIdx.x * 4 + (threadIdx.x >> 6);
    const int lane = threadIdx.x & 63;
    const int sub = lane >> 4;      // edge slot within 4-edge group
    const int fq  = lane & 15;      // feature quad: features fq*4 .. fq*4+3
    const int n  = cnt[node];
    const int* lst = csr + rowstart[node];
    float a0 = 0.f, a1 = 0.f, a2 = 0.f, a3 = 0.f;
    int i = sub;
    for (; i + 4 < n; i += 8) {
        int s0 = lst[i], s1 = lst[i + 4];
        float w0 = dinv[s0], w1 = dinv[s1];
        const float4 v0 = *(const float4*)(x + (size_t)s0 * 64 + fq * 4);
        const float4 v1 = *(const float4*)(x + (size_t)s1 * 64 + fq * 4);
        a0 = fmaf(w0, v0.x, a0); a1 = fmaf(w0, v0.y, a1);
        a2 = fmaf(w0, v0.z, a2); a3 = fmaf(w0, v0.w, a3);
        a0 = fmaf(w1, v1.x, a0); a1 = fmaf(w1, v1.y, a1);
        a2 = fmaf(w1, v1.z, a2); a3 = fmaf(w1, v1.w, a3);
    }
    if (i < n) {
        int s = lst[i];
        float w = dinv[s];
        const float4 v = *(const float4*)(x + (size_t)s * 64 + fq * 4);
        a0 = fmaf(w, v.x, a0); a1 = fmaf(w, v.y, a1);
        a2 = fmaf(w, v.z, a2); a3 = fmaf(w, v.w, a3);
    }
    // combine the 4 edge-slot groups (lanes fq, fq+16, fq+32, fq+48)
    a0 += __shfl_xor(a0, 16); a1 += __shfl_xor(a1, 16);
    a2 += __shfl_xor(a2, 16); a3 += __shfl_xor(a3, 16);
    a0 += __shfl_xor(a0, 32); a1 += __shfl_xor(a1, 32);
    a2 += __shfl_xor(a2, 32); a3 += __shfl_xor(a3, 32);
    if (sub == 0) {
        float dn = dinv[node];
        float4 r = make_float4(dn * a0, dn * a1, dn * a2, dn * a3);
        *(float4*)(y + (size_t)node * 64 + fq * 4) = r;
    }
}

// ---------------------------------------------------------------------------
// Fused tail. Xs node-major [64][192]: phase-2 reads are wave-broadcast
// (2 distinct addrs), phase-1 writes lane-consecutive -> conflict-free.
// W1 streamed from global (L1-hot: 2 KB working set per k-chunk, 8x reuse).
// ---------------------------------------------------------------------------
__global__ __launch_bounds__(256) void k_final(const float* __restrict__ xt, const float* __restrict__ xy,
                                               const float* __restrict__ xc, const float* __restrict__ W1,
                                               const float* __restrict__ b1, const float* __restrict__ W2,
                                               const float* __restrict__ b2, float* __restrict__ out) {
    __shared__ float Xs[64][192];   // 49152 B, node-major
    __shared__ float lg[64][3];
    const int tid = threadIdx.x;
    const int wave = tid >> 6, lane = tid & 63;
    const int nbase = blockIdx.x * 64;

    // ---- phase 1: per-node L2 normalize, store node-major
    for (int g = 0; g < 16; ++g) {
        int m = g * 4 + wave;
        int node = nbase + m;
        float t = 0.f, y = 0.f, c = 0.f;
        if (node < NN) {
            int b = node * 64 + lane;
            t = xt[b]; y = xy[b]; c = xc[b];
        }
        float sst = t * t, ssy = y * y, ssc = c * c;
        #pragma unroll
        for (int off = 32; off > 0; off >>= 1) {
            sst += __shfl_xor(sst, off);
            ssy += __shfl_xor(ssy, off);
            ssc += __shfl_xor(ssc, off);
        }
        t /= fmaxf(sqrtf(sst), 1e-12f);
        y /= fmaxf(sqrtf(ssy), 1e-12f);
        c /= fmaxf(sqrtf(ssc), 1e-12f);
        Xs[m][lane]       = t;
        Xs[m][64 + lane]  = y;
        Xs[m][128 + lane] = c;
    }
    __syncthreads();

    // ---- phase 2: H = relu(X @ W1 + b1); thread = 8 nodes x 4 cols
    const int cg = tid & 31;   // cols cg*4 .. cg*4+3
    const int rg = tid >> 5;   // nodes rg*8 .. rg*8+7
    float acc[8][4];
    {
        float4 bv = *(const float4*)(b1 + cg * 4);
        #pragma unroll
        for (int i = 0; i < 8; ++i) {
            acc[i][0] = bv.x; acc[i][1] = bv.y; acc[i][2] = bv.z; acc[i][3] = bv.w;
        }
    }
    for (int kc = 0; kc < 192; kc += 4) {
        float4 xv[8];
        #pragma unroll
        for (int i = 0; i < 8; ++i) xv[i] = *(const float4*)&Xs[rg * 8 + i][kc];
        float4 w0 = *(const float4*)(W1 + (kc + 0) * 128 + cg * 4);
        float4 w1 = *(const float4*)(W1 + (kc + 1) * 128 + cg * 4);
        float4 w2 = *(const float4*)(W1 + (kc + 2) * 128 + cg * 4);
        float4 w3 = *(const float4*)(W1 + (kc + 3) * 128 + cg * 4);
        #pragma unroll
        for (int i = 0; i < 8; ++i) {
            float4 xi = xv[i];
            acc[i][0] = fmaf(xi.x, w0.x, acc[i][0]); acc[i][1] = fmaf(xi.x, w0.y, acc[i][1]);
            acc[i][2] = fmaf(xi.x, w0.z, acc[i][2]); acc[i][3] = fmaf(xi.x, w0.w, acc[i][3]);
            acc[i][0] = fmaf(xi.y, w1.x, acc[i][0]); acc[i][1] = fmaf(xi.y, w1.y, acc[i][1]);
            acc[i][2] = fmaf(xi.y, w1.z, acc[i][2]); acc[i][3] = fmaf(xi.y, w1.w, acc[i][3]);
            acc[i][0] = fmaf(xi.z, w2.x, acc[i][0]); acc[i][1] = fmaf(xi.z, w2.y, acc[i][1]);
            acc[i][2] = fmaf(xi.z, w2.z, acc[i][2]); acc[i][3] = fmaf(xi.z, w2.w, acc[i][3]);
            acc[i][0] = fmaf(xi.w, w3.x, acc[i][0]); acc[i][1] = fmaf(xi.w, w3.y, acc[i][1]);
            acc[i][2] = fmaf(xi.w, w3.z, acc[i][2]); acc[i][3] = fmaf(xi.w, w3.w, acc[i][3]);
        }
    }

    // ---- epilogue: logits = relu(H) @ W2, reduce across the 32-lane col half
    float w2c[4][3];
    #pragma unroll
    for (int j = 0; j < 4; ++j)
        #pragma unroll
        for (int q = 0; q < 3; ++q) w2c[j][q] = W2[(cg * 4 + j) * 3 + q];

    #pragma unroll
    for (int i = 0; i < 8; ++i) {
        float p0 = 0.f, p1 = 0.f, p2 = 0.f;
        #pragma unroll
        for (int j = 0; j < 4; ++j) {
            float h = fmaxf(acc[i][j], 0.f);
            p0 = fmaf(h, w2c[j][0], p0);
            p1 = fmaf(h, w2c[j][1], p1);
            p2 = fmaf(h, w2c[j][2], p2);
        }
        #pragma unroll
        for (int off = 16; off > 0; off >>= 1) {  // stays within 32-lane half
            p0 += __shfl_xor(p0, off);
            p1 += __shfl_xor(p1, off);
            p2 += __shfl_xor(p2, off);
        }
        if (cg == 0) {
            lg[rg * 8 + i][0] = p0;
            lg[rg * 8 + i][1] = p1;
            lg[rg * 8 + i][2] = p2;
        }
    }
    __syncthreads();

    // ---- softmax + weighted sum, coalesced output
    for (int g = 0; g < 16; ++g) {
        int m = g * 4 + wave;
        int node = nbase + m;
        if (node < NN) {
            float l0 = lg[m][0] + b2[0];
            float l1 = lg[m][1] + b2[1];
            float l2 = lg[m][2] + b2[2];
            float mx = fmaxf(l0, fmaxf(l1, l2));
            float e0 = __expf(l0 - mx), e1 = __expf(l1 - mx), e2 = __expf(l2 - mx);
            float inv = 1.0f / (e0 + e1 + e2);
            float t = Xs[m][lane], y = Xs[m][64 + lane], c = Xs[m][128 + lane];
            out[node * 64 + lane] = (e0 * t + e1 * y + e2 * c) * inv;
        }
    }
}

// ---------------------------------------------------------------------------
extern "C" void kernel_launch(void* const* d_in, const int* in_sizes, int n_in,
                              void* d_out, int out_size, void* d_ws, size_t ws_size,
                              hipStream_t stream) {
    const float* init_feat = (const float*)d_in[0];
    const float* W1 = (const float*)d_in[1];
    const float* b1 = (const float*)d_in[2];
    const float* W2 = (const float*)d_in[3];
    const float* b2 = (const float*)d_in[4];
    const int* ei[3] = {(const int*)d_in[5], (const int*)d_in[6], (const int*)d_in[7]}; // title, year, cat

    float* TMP = (float*)d_out;   // d_out doubles as ping-pong temp (fully rewritten before reads)

    float* B1 = (float*)d_ws;                     // title out   [N*64]
    float* B2 = B1 + (size_t)NN * 64;             // year out    [N*64]
    float* B3 = B2 + (size_t)NN * 64;             // cat temp    [N*64]
    float* dinvA = B3 + (size_t)NN * 64;          // [3*N]
    int* cntA = (int*)(dinvA + 3 * NN);           // [3*N]
    int* curA = cntA + 3 * NN;                    // [3*N]
    int* allocA = curA + 3 * NN;                  // [4]
    int* rowA = allocA + 4;                       // [3*N]
    int* csrA = rowA + 3 * NN;                    // [3*E]

    const int TB = 256;
    const int e3Grid = (3 * NE + TB - 1) / TB;
    const int nGrid = (NN + TB - 1) / TB;
    const int gatherGrid = NN / 4;                // exact
    const int finalGrid = (NN + 63) / 64;

    hipMemsetAsync(cntA, 0, (size_t)(6 * NN + 4) * sizeof(int), stream);

    k_cnt3<<<e3Grid, TB, 0, stream>>>(ei[0], ei[1], ei[2], cntA);
    k_dinv<<<(3 * NN + TB - 1) / TB, TB, 0, stream>>>(cntA, dinvA);
    for (int s = 0; s < 3; ++s)
        k_alloc<<<nGrid, TB, 0, stream>>>(cntA + s * NN, rowA + s * NN, allocA + s);
    k_scat3<<<e3Grid, TB, 0, stream>>>(ei[0], ei[1], ei[2], rowA, curA, csrA);

    #define GATHER(xp, yp, s) \
        k_gather<<<gatherGrid, TB, 0, stream>>>((xp), (yp), csrA + (size_t)(s) * NE, \
                                                rowA + (s) * NN, cntA + (s) * NN, dinvA + (s) * NN)
    GATHER(init_feat, TMP, 0);   // title conv 1
    GATHER(TMP, B1, 0);          // title conv 2 -> B1
    GATHER(init_feat, B2, 1);    // year conv    -> B2
    GATHER(init_feat, TMP, 2);   // cat conv 1
    GATHER(TMP, B3, 2);          // cat conv 2
    GATHER(B3, TMP, 2);          // cat conv 3   -> TMP (= d_out)
    #undef GATHER

    k_final<<<finalGrid, TB, 0, stream>>>(B1, B2, TMP, W1, b1, W2, b2, TMP);
}